// Round 5
// baseline (718.935 us; speedup 1.0000x reference)
//
#include <hip/hip_runtime.h>
#include <hip/hip_bf16.h>
#include <math.h>

#define B_   4
#define T_   2048
#define C_   2048
#define NH_  16
#define HD_  128
#define KVD_ 1024

typedef __attribute__((ext_vector_type(4))) float f32x4;
typedef __attribute__((ext_vector_type(16))) float f32x16;
typedef __attribute__((ext_vector_type(8))) short bf16x8;

__device__ __forceinline__ void async_copy16(const __hip_bfloat16* g, __hip_bfloat16* l) {
  __builtin_amdgcn_global_load_lds((const __attribute__((address_space(1))) void*)g,
                                   (__attribute__((address_space(3))) void*)l,
                                   16, 0, 0);
}

__device__ __forceinline__ float bf2f(__hip_bfloat16 h) { return __bfloat162float(h); }

// ---------------- f32 -> bf16 convert (x) ----------------
__global__ __launch_bounds__(256) void f32_to_bf16_k(const float* __restrict__ src,
                                                     __hip_bfloat16* __restrict__ dst, int n4) {
  int i = blockIdx.x * 256 + threadIdx.x;
  if (i >= n4) return;
  float4 f = ((const float4*)src)[i];
  __hip_bfloat16 o[4] = {__float2bfloat16(f.x), __float2bfloat16(f.y),
                         __float2bfloat16(f.z), __float2bfloat16(f.w)};
  *(uint2*)(dst + (size_t)i * 4) = *(uint2*)o;
}

// ---------------- transpose + convert: WT[n][k] = bf16(W[k][n]) ----------------
__global__ __launch_bounds__(256) void transpose_f32_bf16_k(const float* __restrict__ W,
                                                            __hip_bfloat16* __restrict__ WT,
                                                            int K, int N) {
  __shared__ float tile[32][33];
  int bx = blockIdx.x * 32;  // n
  int by = blockIdx.y * 32;  // k
  int tx = threadIdx.x, ty = threadIdx.y;
  for (int i = ty; i < 32; i += 8)
    tile[i][tx] = W[(size_t)(by + i) * N + (bx + tx)];
  __syncthreads();
  for (int i = ty; i < 32; i += 8)
    WT[(size_t)(bx + i) * K + (by + tx)] = __float2bfloat16(tile[tx][i]);
}

// ---------------- V transpose: Vt[b][g][d][t] = kv[b][t][512 + g*128 + d] ----------------
__global__ __launch_bounds__(256) void vtrans_k(const __hip_bfloat16* __restrict__ kv,
                                                __hip_bfloat16* __restrict__ vt) {
  __shared__ __hip_bfloat16 tile[32][33];
  int bg = blockIdx.z;            // b*4+g
  int d0 = blockIdx.y * 32;
  int t0 = blockIdx.x * 32;
  int tx = threadIdx.x, ty = threadIdx.y;
  int b = bg >> 2, g = bg & 3;
  const __hip_bfloat16* src = kv + (size_t)b * T_ * KVD_ + 512 + g * HD_;
  for (int i = ty; i < 32; i += 8)
    tile[i][tx] = src[(size_t)(t0 + i) * KVD_ + d0 + tx];
  __syncthreads();
  __hip_bfloat16* dst = vt + (size_t)bg * HD_ * T_;
  for (int i = ty; i < 32; i += 8)
    dst[(size_t)(d0 + i) * T_ + t0 + tx] = tile[tx][i];
}

// ---------------- row l2norm (in place, bf16), scale folded via `extra` ----------------
template<int PER>
__global__ __launch_bounds__(256) void rownorm_k(__hip_bfloat16* __restrict__ buf,
                                                 int stride, float extra) {
  const int tid = threadIdx.x;
  __hip_bfloat16* p = buf + (size_t)blockIdx.x * stride;
  float v[PER];
  float ss = 0.f;
  #pragma unroll
  for (int e = 0; e < PER; ++e) { v[e] = bf2f(p[tid + e * 256]); ss += v[e] * v[e]; }
  #pragma unroll
  for (int off = 32; off >= 1; off >>= 1) ss += __shfl_xor(ss, off, 64);
  __shared__ float wsum[4];
  if ((tid & 63) == 0) wsum[tid >> 6] = ss;
  __syncthreads();
  float tot = wsum[0] + wsum[1] + wsum[2] + wsum[3];
  float sc = extra / (sqrtf(tot) + 1e-12f);
  #pragma unroll
  for (int e = 0; e < PER; ++e) p[tid + e * 256] = __float2bfloat16(v[e] * sc);
}

// ---------------- GEMM: C[M][N] = A[M][K] @ BT[N][K]^T, bf16 in, OutT out ----------------
template<typename OutT>
__global__ __launch_bounds__(256) void gemm_bt_k(const __hip_bfloat16* __restrict__ A,
                                                 const __hip_bfloat16* __restrict__ BT,
                                                 OutT* __restrict__ Cc,
                                                 int M, int N, int K) {
  __shared__ alignas(16) __hip_bfloat16 As[128 * 32];
  __shared__ alignas(16) __hip_bfloat16 Bs[128 * 32];
  const int tid = threadIdx.x;
  const int bm = blockIdx.y * 128;
  const int bn = blockIdx.x * 128;
  const int wave = tid >> 6, lane = tid & 63;
  const int wr = (wave >> 1) * 64, wc = (wave & 1) * 64;
  const int lm = lane & 15, lk = (lane >> 4) * 8;
  const size_t Kz = (size_t)K;
  const __hip_bfloat16* a0 = A + (size_t)(bm + (tid >> 2)) * Kz + (size_t)((tid & 3) * 8);
  const __hip_bfloat16* b0 = BT + (size_t)(bn + (tid >> 2)) * Kz + (size_t)((tid & 3) * 8);
  const __hip_bfloat16* a1 = a0 + 64 * Kz;
  const __hip_bfloat16* b1 = b0 + 64 * Kz;
  f32x4 acc[4][4] = {};
  for (int k0 = 0; k0 < K; k0 += 32) {
    async_copy16(a0 + k0, As + tid * 8);
    async_copy16(a1 + k0, As + 2048 + tid * 8);
    async_copy16(b0 + k0, Bs + tid * 8);
    async_copy16(b1 + k0, Bs + 2048 + tid * 8);
    __syncthreads();
    bf16x8 af[4], bfr[4];
    #pragma unroll
    for (int t = 0; t < 4; ++t) {
      af[t]  = *(const bf16x8*)(As + (wr + t * 16 + lm) * 32 + lk);
      bfr[t] = *(const bf16x8*)(Bs + (wc + t * 16 + lm) * 32 + lk);
    }
    #pragma unroll
    for (int mt = 0; mt < 4; ++mt)
      #pragma unroll
      for (int nt = 0; nt < 4; ++nt)
        acc[mt][nt] = __builtin_amdgcn_mfma_f32_16x16x32_bf16(af[mt], bfr[nt], acc[mt][nt], 0, 0, 0);
    __syncthreads();
  }
  const int r0 = (lane >> 4) * 4;
  #pragma unroll
  for (int mt = 0; mt < 4; ++mt)
    #pragma unroll
    for (int nt = 0; nt < 4; ++nt)
      #pragma unroll
      for (int r = 0; r < 4; ++r) {
        int gr = bm + wr + mt * 16 + r0 + r;
        int gc = bn + wc + nt * 16 + lm;
        float v = acc[mt][nt][r];
        if constexpr (__is_same(OutT, float))
          Cc[(size_t)gr * N + gc] = v;
        else
          Cc[(size_t)gr * N + gc] = __float2bfloat16(v);
      }
}

// ---------------- flash attention v4: 32x32x16 MFMA, 128 q-rows/block ----------------
// Scores bounded (|S|<=0.0884) -> fixed-shift softmax, no running max (round-4 math).
// Per wave: 32 q-rows; Q-frags direct from global; K/V single-buffered LDS (50KB -> 3 blocks/CU).
// 32x32x16 layouts: A/B: m|n=lane&31, k=(lane>>5)*8+j. C/D: col=lane&31,
// row=(reg&3)+8*(reg>>2)+4*(lane>>5)  [m74/m101 verified].
// grid (T/128, NH, B); block 256.
__global__ __launch_bounds__(256) void attn_k(const __hip_bfloat16* __restrict__ q,
                                              const __hip_bfloat16* __restrict__ kv,
                                              const __hip_bfloat16* __restrict__ vt,
                                              __hip_bfloat16* __restrict__ y) {
  const int qt = (int)gridDim.x - 1 - (int)blockIdx.x;  // heavy blocks first
  const int h  = blockIdx.y;
  const int b  = blockIdx.z;
  const int g  = h >> 2;
  const int tid = threadIdx.x;
  const int wave = tid >> 6, lane = tid & 63;
  const int ln = lane & 31, half = lane >> 5;

  __shared__ alignas(16) __hip_bfloat16 Ks[64 * 128];    // 16 KB, XOR-swizzled rows
  __shared__ alignas(16) __hip_bfloat16 Vts[128 * 64];   // 16 KB, XOR-swizzled rows
  __shared__ alignas(16) __hip_bfloat16 Ps[4 * 32 * 72]; // 18 KB, wave-private P (stride 72)

  // Q fragments direct from global (once per block; rows reused across all K-tiles)
  const int qrow = qt * 128 + wave * 32 + ln;
  const __hip_bfloat16* qp = q + ((size_t)b * T_ + qrow) * C_ + h * HD_ + half * 8;
  bf16x8 qa[8];
  #pragma unroll
  for (int kc = 0; kc < 8; ++kc)
    qa[kc] = *(const bf16x8*)(qp + kc * 16);

  const __hip_bfloat16* kb = kv + (size_t)b * T_ * KVD_ + g * HD_;
  const __hip_bfloat16* vb = vt + (size_t)(b * 4 + g) * HD_ * T_;
  __hip_bfloat16* Psw = Ps + wave * (32 * 72);

  float l_acc[16];
  #pragma unroll
  for (int r = 0; r < 16; ++r) l_acc[r] = 0.f;
  f32x16 o_acc[4] = {};

  const int ntiles = 2 * (qt + 1);
  for (int it = 0; it < ntiles; ++it) {
    const int j0 = it * 64;
    // stage K tile (64 x 128) and V^T tile (128 x 64), XOR-swizzled 16B chunks
    #pragma unroll
    for (int e = 0; e < 4; ++e) {
      int idx = tid + e * 256;
      int row = idx >> 4, c = idx & 15;
      async_copy16(kb + (size_t)(j0 + row) * KVD_ + ((c ^ (row & 15)) * 8), Ks + idx * 8);
    }
    #pragma unroll
    for (int e = 0; e < 4; ++e) {
      int idx = tid + e * 256;
      int row = idx >> 3, c = idx & 7;
      async_copy16(vb + (size_t)row * T_ + j0 + ((c ^ (row & 7)) * 8), Vts + idx * 8);
    }
    __syncthreads();  // drains staging vmcnt

    // S = Q K^T, one 32-col strip at a time (caps live sv regs at 16)
    #pragma unroll
    for (int st = 0; st < 2; ++st) {
      f32x16 sv = {};
      #pragma unroll
      for (int kc = 0; kc < 8; ++kc) {
        int row = st * 32 + ln;
        int c = kc * 2 + half;
        bf16x8 kf = *(const bf16x8*)(Ks + row * 128 + ((c ^ (row & 15)) * 8));
        sv = __builtin_amdgcn_mfma_f32_32x32x16_bf16(qa[kc], kf, sv, 0, 0, 0);
      }
      const int sg = j0 + st * 32 + ln;
      #pragma unroll
      for (int r = 0; r < 16; ++r) {
        int crow = (r & 3) + 8 * (r >> 2) + 4 * half;
        int tq = qt * 128 + wave * 32 + crow;
        float pv = (sg > tq) ? 0.f : __expf(sv[r]);
        l_acc[r] += pv;
        Psw[crow * 72 + st * 32 + ln] = __float2bfloat16(pv);
      }
    }
    __asm__ volatile("s_waitcnt lgkmcnt(0)" ::: "memory");  // P visible to own wave
    // O += P V
    #pragma unroll
    for (int kc = 0; kc < 4; ++kc) {
      bf16x8 pf = *(const bf16x8*)(Psw + ln * 72 + ((kc * 2 + half) * 8));
      #pragma unroll
      for (int nt = 0; nt < 4; ++nt) {
        int row = nt * 32 + ln;
        int c = kc * 2 + half;
        bf16x8 vf = *(const bf16x8*)(Vts + row * 64 + ((c ^ (row & 7)) * 8));
        o_acc[nt] = __builtin_amdgcn_mfma_f32_32x32x16_bf16(pf, vf, o_acc[nt], 0, 0, 0);
      }
    }
    __syncthreads();  // K/V buffers reused next iter
  }

  // one-time row-sum reduce over the 32 column-lanes (rows differ across halves: no off=32)
  #pragma unroll
  for (int r = 0; r < 16; ++r)
    #pragma unroll
    for (int off = 1; off <= 16; off <<= 1)
      l_acc[r] += __shfl_xor(l_acc[r], off, 64);

  // epilogue: y[b][t][h*HD + d] = O / l
  #pragma unroll
  for (int nt = 0; nt < 4; ++nt)
    #pragma unroll
    for (int r = 0; r < 16; ++r) {
      int crow = (r & 3) + 8 * (r >> 2) + 4 * half;
      int t = qt * 128 + wave * 32 + crow;
      int d = nt * 32 + ln;
      y[((size_t)b * T_ + t) * C_ + h * HD_ + d] = __float2bfloat16(o_acc[nt][r] / l_acc[r]);
    }
}

extern "C" void kernel_launch(void* const* d_in, const int* in_sizes, int n_in,
                              void* d_out, int out_size, void* d_ws, size_t ws_size,
                              hipStream_t stream) {
  (void)in_sizes; (void)n_in; (void)out_size; (void)ws_size;
  const float* x     = (const float*)d_in[0];
  const float* Wq    = (const float*)d_in[1];
  const float* Wkv   = (const float*)d_in[2];
  const float* Wproj = (const float*)d_in[3];
  char* ws = (char*)d_ws;
  __hip_bfloat16* xb     = (__hip_bfloat16*)(ws);               // 32 MB (reused as y)
  __hip_bfloat16* WqT    = (__hip_bfloat16*)(ws + 33554432);    //  8 MB
  __hip_bfloat16* WkvT   = (__hip_bfloat16*)(ws + 41943040);    //  4 MB
  __hip_bfloat16* WprojT = (__hip_bfloat16*)(ws + 46137344);    //  8 MB
  __hip_bfloat16* qn     = (__hip_bfloat16*)(ws + 54525952);    // 32 MB
  __hip_bfloat16* kvb    = (__hip_bfloat16*)(ws + 88080384);    // 16 MB
  __hip_bfloat16* y      = xb;                                  // alias: xb dead after kv-gemm
  __hip_bfloat16* vt     = (__hip_bfloat16*)d_out;              // 16 MB scratch in d_out (dead before final gemm)
  float* out             = (float*)d_out;

  f32_to_bf16_k<<<16384, 256, 0, stream>>>(x, xb, 4194304);
  transpose_f32_bf16_k<<<dim3(64, 64), dim3(32, 8), 0, stream>>>(Wq, WqT, 2048, 2048);
  transpose_f32_bf16_k<<<dim3(32, 64), dim3(32, 8), 0, stream>>>(Wkv, WkvT, 2048, 1024);
  transpose_f32_bf16_k<<<dim3(64, 64), dim3(32, 8), 0, stream>>>(Wproj, WprojT, 2048, 2048);
  gemm_bt_k<__hip_bfloat16><<<dim3(16, 64), 256, 0, stream>>>(xb, WqT, qn, 8192, 2048, 2048);
  gemm_bt_k<__hip_bfloat16><<<dim3(8, 64), 256, 0, stream>>>(xb, WkvT, kvb, 8192, 1024, 2048);
  rownorm_k<8><<<8192, 256, 0, stream>>>(qn, 2048, 0.08838834764831845f);  // 1/sqrt(HD) folded
  rownorm_k<2><<<8192, 256, 0, stream>>>(kvb, 1024, 1.0f);
  vtrans_k<<<dim3(64, 4, 16), dim3(32, 8), 0, stream>>>(kvb, vt);
  attn_k<<<dim3(16, 16, 4), 256, 0, stream>>>(qn, kvb, vt, y);
  gemm_bt_k<float><<<dim3(16, 64), 256, 0, stream>>>(y, WprojT, out, 8192, 2048, 2048);
}